// Round 1
// baseline (554.246 us; speedup 1.0000x reference)
//
#include <hip/hip_runtime.h>
#include <hip/hip_bf16.h>

#define N_NODES 50000
#define N_EDGES 800000
#define IN_CH   128
#define HID_CH  128
#define OUT_CH  32

// ---------------------------------------------------------------------------
// CSR build: degree histogram
__global__ void k_degree(const int* __restrict__ edges, int* __restrict__ deg) {
    int e = blockIdx.x * blockDim.x + threadIdx.x;
    if (e >= N_EDGES) return;
    int d = edges[N_EDGES + e];   // dst row
    atomicAdd(&deg[d], 1);
}

// single-block exclusive scan over deg[0..N) -> rowstart[0..N]
__global__ void k_scan(const int* __restrict__ deg, int* __restrict__ rowstart) {
    __shared__ int sums[1024];
    const int t = threadIdx.x;
    const int CH = (N_NODES + 1023) / 1024;  // 49
    int begin = t * CH;
    int end = begin + CH; if (end > N_NODES) end = N_NODES;
    int local = 0;
    for (int i = begin; i < end; i++) local += deg[i];
    sums[t] = local;
    __syncthreads();
    for (int off = 1; off < 1024; off <<= 1) {
        int v = (t >= off) ? sums[t - off] : 0;
        __syncthreads();
        sums[t] += v;
        __syncthreads();
    }
    int run = sums[t] - local;   // exclusive prefix at chunk start
    for (int i = begin; i < end; i++) { rowstart[i] = run; run += deg[i]; }
    if (t == 1023) rowstart[N_NODES] = sums[1023];
}

__global__ void k_fill(const int* __restrict__ edges, const int* __restrict__ rowstart,
                       int* __restrict__ cursor, int* __restrict__ csr_src) {
    int e = blockIdx.x * blockDim.x + threadIdx.x;
    if (e >= N_EDGES) return;
    int s = edges[e];
    int d = edges[N_EDGES + e];
    int pos = atomicAdd(&cursor[d], 1);
    csr_src[rowstart[d] + pos] = s;
}

// ---------------------------------------------------------------------------
// Pull-based mean aggregation: one 64-lane wave per node, float2 per lane (128 ch)
__global__ __launch_bounds__(256) void k_agg(const float* __restrict__ feat,
                                             const int* __restrict__ csr_src,
                                             const int* __restrict__ rowstart,
                                             float* __restrict__ outmean) {
    int node = blockIdx.x * 4 + (threadIdx.x >> 6);
    if (node >= N_NODES) return;
    int lane = threadIdx.x & 63;
    int s = rowstart[node];
    int e = rowstart[node + 1];
    const float2* f2 = (const float2*)feat;
    float ax = 0.f, ay = 0.f;
    for (int j = s; j < e; j++) {
        int src = csr_src[j];
        float2 v = f2[src * 64 + lane];
        ax += v.x; ay += v.y;
    }
    float inv = 1.0f / fmaxf((float)(e - s), 1.0f);
    float2* o2 = (float2*)outmean;
    o2[node * 64 + lane] = make_float2(ax * inv, ay * inv);
}

// ---------------------------------------------------------------------------
// h = relu(mean @ W1l + x @ W1r + b1)   [M=50000, K=128(+128), N=128]
// 64-row tile in LDS (64x256 f32 = 64KB exactly), 256 threads, 8x4 per-thread tile.
__global__ __launch_bounds__(256) void k_gemm_hidden(const float* __restrict__ mean,
                                                     const float* __restrict__ x,
                                                     const float* __restrict__ W1l,
                                                     const float* __restrict__ W1r,
                                                     const float* __restrict__ b1,
                                                     float* __restrict__ h) {
    __shared__ float a_lds[64][256];   // [row][k] ; k<128 = mean, k>=128 = x
    const int tid = threadIdx.x;
    const int row0 = blockIdx.x * 64;

    // stage A tile: 4096 float4 loads across 256 threads (16 each), coalesced
    const float4* mean4 = (const float4*)mean;
    const float4* x4    = (const float4*)x;
#pragma unroll
    for (int m = 0; m < 16; m++) {
        int idx = m * 256 + tid;        // 0..4095
        int row = idx >> 6;             // 0..63
        int c4  = idx & 63;             // float4 index in concat 256 floats
        int grow = row0 + row;
        float4 v = make_float4(0.f, 0.f, 0.f, 0.f);
        if (grow < N_NODES) {
            if (c4 < 32) v = mean4[grow * 32 + c4];
            else         v = x4[grow * 32 + (c4 - 32)];
        }
        *((float4*)&a_lds[row][c4 * 4]) = v;
    }
    __syncthreads();

    const int tx = tid & 31;    // output cols tx*4 .. tx*4+3
    const int ty = tid >> 5;    // rows ty*8 .. ty*8+7
    float acc[8][4];
#pragma unroll
    for (int i = 0; i < 8; i++)
#pragma unroll
        for (int j = 0; j < 4; j++) acc[i][j] = 0.f;

    const float4* Wl4 = (const float4*)W1l;   // [128][32]
    const float4* Wr4 = (const float4*)W1r;

    for (int k = 0; k < 128; k++) {
        float4 wl = Wl4[k * 32 + tx];
        float4 wr = Wr4[k * 32 + tx];
#pragma unroll
        for (int i = 0; i < 8; i++) {
            float a = a_lds[ty * 8 + i][k];
            acc[i][0] += a * wl.x; acc[i][1] += a * wl.y;
            acc[i][2] += a * wl.z; acc[i][3] += a * wl.w;
        }
#pragma unroll
        for (int i = 0; i < 8; i++) {
            float a = a_lds[ty * 8 + i][128 + k];
            acc[i][0] += a * wr.x; acc[i][1] += a * wr.y;
            acc[i][2] += a * wr.z; acc[i][3] += a * wr.w;
        }
    }

    float4 bias = ((const float4*)b1)[tx];
    float4* h4 = (float4*)h;
#pragma unroll
    for (int i = 0; i < 8; i++) {
        int grow = row0 + ty * 8 + i;
        if (grow < N_NODES) {
            float4 r;
            r.x = fmaxf(acc[i][0] + bias.x, 0.f);
            r.y = fmaxf(acc[i][1] + bias.y, 0.f);
            r.z = fmaxf(acc[i][2] + bias.z, 0.f);
            r.w = fmaxf(acc[i][3] + bias.w, 0.f);
            h4[grow * 32 + tx] = r;
        }
    }
}

// ---------------------------------------------------------------------------
// out = log_softmax(mean2 @ W2l + h @ W2r + b2)  [M=50000, K=128, N=32]
// 32 lanes per row (one output each), shuffle-reduce width 32 for softmax.
__global__ __launch_bounds__(256) void k_gemm_out(const float* __restrict__ mean2,
                                                  const float* __restrict__ h,
                                                  const float* __restrict__ W2l,
                                                  const float* __restrict__ W2r,
                                                  const float* __restrict__ b2,
                                                  float* __restrict__ out) {
    int rg  = threadIdx.x >> 5;            // 0..7 row group
    int j   = threadIdx.x & 31;            // output channel
    int row = blockIdx.x * 8 + rg;
    if (row >= N_NODES) return;

    float acc = b2[j];
    const float* mrow = mean2 + row * HID_CH;
    const float* hrow = h + row * HID_CH;
    for (int k = 0; k < HID_CH; k++) {
        float m  = mrow[k];
        float hh = hrow[k];
        acc += m * W2l[k * 32 + j] + hh * W2r[k * 32 + j];
    }
    // log_softmax over the 32 lanes of this row group
    float mx = acc;
    for (int o = 16; o > 0; o >>= 1) mx = fmaxf(mx, __shfl_xor(mx, o, 32));
    float ex = __expf(acc - mx);
    float s = ex;
    for (int o = 16; o > 0; o >>= 1) s += __shfl_xor(s, o, 32);
    out[row * 32 + j] = acc - mx - logf(s);
}

// ---------------------------------------------------------------------------
extern "C" void kernel_launch(void* const* d_in, const int* in_sizes, int n_in,
                              void* d_out, int out_size, void* d_ws, size_t ws_size,
                              hipStream_t stream) {
    const float* x     = (const float*)d_in[0];
    const int*   edges = (const int*)d_in[1];     // [2][E] int32
    const float* W1l   = (const float*)d_in[2];
    const float* W1r   = (const float*)d_in[3];
    const float* b1    = (const float*)d_in[4];
    const float* W2l   = (const float*)d_in[5];
    const float* W2r   = (const float*)d_in[6];
    const float* b2    = (const float*)d_in[7];
    float* out = (float*)d_out;

    // workspace layout (256B-aligned)
    char* ws = (char*)d_ws;
    size_t off = 0;
    auto alloc = [&](size_t bytes) { size_t p = off; off += (bytes + 255) & ~(size_t)255; return p; };
    int*   deg      = (int*)(ws + alloc(sizeof(int) * N_NODES));
    int*   cursor   = (int*)(ws + alloc(sizeof(int) * N_NODES));
    int*   rowstart = (int*)(ws + alloc(sizeof(int) * (N_NODES + 1)));
    int*   csr_src  = (int*)(ws + alloc(sizeof(int) * N_EDGES));
    float* mean     = (float*)(ws + alloc(sizeof(float) * (size_t)N_NODES * HID_CH));
    float* h        = (float*)(ws + alloc(sizeof(float) * (size_t)N_NODES * HID_CH));

    hipMemsetAsync(deg, 0, sizeof(int) * N_NODES, stream);
    hipMemsetAsync(cursor, 0, sizeof(int) * N_NODES, stream);

    const int eblocks = (N_EDGES + 255) / 256;
    k_degree<<<eblocks, 256, 0, stream>>>(edges, deg);
    k_scan<<<1, 1024, 0, stream>>>(deg, rowstart);
    k_fill<<<eblocks, 256, 0, stream>>>(edges, rowstart, cursor, csr_src);

    // layer 1
    k_agg<<<(N_NODES + 3) / 4, 256, 0, stream>>>(x, csr_src, rowstart, mean);
    k_gemm_hidden<<<(N_NODES + 63) / 64, 256, 0, stream>>>(mean, x, W1l, W1r, b1, h);

    // layer 2 (reuse `mean` buffer for the second aggregation)
    k_agg<<<(N_NODES + 3) / 4, 256, 0, stream>>>(h, csr_src, rowstart, mean);
    k_gemm_out<<<(N_NODES + 7) / 8, 256, 0, stream>>>(mean, h, W2l, W2r, b2, out);
}

// Round 2
// 345.270 us; speedup vs baseline: 1.6053x; 1.6053x over previous
//
#include <hip/hip_runtime.h>
#include <hip/hip_bf16.h>

#define N_NODES 50000
#define N_EDGES 800000
#define IN_CH   128
#define HID_CH  128
#define OUT_CH  32
#define NCHUNK  196   // ceil(50000/256)

// ---------------------------------------------------------------------------
// CSR build
__global__ void k_degree(const int* __restrict__ edges, int* __restrict__ deg) {
    int e = blockIdx.x * blockDim.x + threadIdx.x;
    if (e >= N_EDGES) return;
    atomicAdd(&deg[edges[N_EDGES + e]], 1);
}

// per-256-chunk sums (coalesced)
__global__ __launch_bounds__(256) void k_chunksum(const int* __restrict__ deg,
                                                  int* __restrict__ chunksum) {
    int t = threadIdx.x;
    int i = blockIdx.x * 256 + t;
    int v = (i < N_NODES) ? deg[i] : 0;
#pragma unroll
    for (int off = 32; off > 0; off >>= 1) v += __shfl_down(v, off, 64);
    __shared__ int p[4];
    if ((t & 63) == 0) p[t >> 6] = v;
    __syncthreads();
    if (t == 0) chunksum[blockIdx.x] = p[0] + p[1] + p[2] + p[3];
}

// exclusive scan of the 196 chunk sums (single tiny block)
__global__ __launch_bounds__(256) void k_chunkscan(const int* __restrict__ chunksum,
                                                   int* __restrict__ chunkoff,
                                                   int* __restrict__ rowstart) {
    __shared__ int s[256];
    int t = threadIdx.x;
    int v = (t < NCHUNK) ? chunksum[t] : 0;
    s[t] = v;
    __syncthreads();
    for (int off = 1; off < 256; off <<= 1) {
        int u = (t >= off) ? s[t - off] : 0;
        __syncthreads();
        s[t] += u;
        __syncthreads();
    }
    if (t < NCHUNK) chunkoff[t] = s[t] - v;   // exclusive prefix
    if (t == 255) rowstart[N_NODES] = s[255];
}

// rowstart[i] = chunkoff[b] + exclusive-scan within chunk (coalesced)
__global__ __launch_bounds__(256) void k_rowstart(const int* __restrict__ deg,
                                                  const int* __restrict__ chunkoff,
                                                  int* __restrict__ rowstart) {
    __shared__ int s[256];
    int t = threadIdx.x;
    int i = blockIdx.x * 256 + t;
    int v = (i < N_NODES) ? deg[i] : 0;
    s[t] = v;
    __syncthreads();
    for (int off = 1; off < 256; off <<= 1) {
        int u = (t >= off) ? s[t - off] : 0;
        __syncthreads();
        s[t] += u;
        __syncthreads();
    }
    if (i < N_NODES) rowstart[i] = chunkoff[blockIdx.x] + s[t] - v;
}

__global__ void k_fill(const int* __restrict__ edges, const int* __restrict__ rowstart,
                       int* __restrict__ cursor, int* __restrict__ csr_src) {
    int e = blockIdx.x * blockDim.x + threadIdx.x;
    if (e >= N_EDGES) return;
    int s = edges[e];
    int d = edges[N_EDGES + e];
    int pos = atomicAdd(&cursor[d], 1);
    csr_src[rowstart[d] + pos] = s;
}

// ---------------------------------------------------------------------------
// Layer-1 mean aggregation: one 64-lane wave per node, float2 per lane (128 ch).
// Indices loaded coalesced in chunks of 64, broadcast via shuffle.
__global__ __launch_bounds__(256) void k_agg(const float* __restrict__ feat,
                                             const int* __restrict__ csr_src,
                                             const int* __restrict__ rowstart,
                                             float* __restrict__ outmean) {
    int node = blockIdx.x * 4 + (threadIdx.x >> 6);
    if (node >= N_NODES) return;
    int lane = threadIdx.x & 63;
    int s = rowstart[node];
    int e = rowstart[node + 1];
    const float2* f2 = (const float2*)feat;
    float ax = 0.f, ay = 0.f;
    for (int base = s; base < e; base += 64) {
        int idx = (base + lane < e) ? csr_src[base + lane] : 0;
        int m = e - base; if (m > 64) m = 64;
        for (int q = 0; q < m; q++) {
            int src = __shfl(idx, q, 64);
            float2 v = f2[src * 64 + lane];
            ax += v.x; ay += v.y;
        }
    }
    float inv = 1.0f / fmaxf((float)(e - s), 1.0f);
    ((float2*)outmean)[node * 64 + lane] = make_float2(ax * inv, ay * inv);
}

// ---------------------------------------------------------------------------
// h = relu(mean @ W1l + x @ W1r + b1)   [M=50000, K=256 concat, N=128]
// 64-row tile (64x256 f32 = 64KB LDS), 256 threads, 8 rows x 4 cols / thread,
// 4-wide k unroll with b128 LDS reads (wave sees 2 distinct addrs -> free 2-way).
__global__ __launch_bounds__(256) void k_gemm_hidden(const float* __restrict__ mean,
                                                     const float* __restrict__ x,
                                                     const float* __restrict__ W1l,
                                                     const float* __restrict__ W1r,
                                                     const float* __restrict__ b1,
                                                     float* __restrict__ h) {
    __shared__ float a_lds[64][256];
    const int tid = threadIdx.x;
    const int row0 = blockIdx.x * 64;

    const float4* mean4 = (const float4*)mean;
    const float4* x4    = (const float4*)x;
#pragma unroll
    for (int m = 0; m < 16; m++) {
        int idx = m * 256 + tid;
        int row = idx >> 6;
        int c4  = idx & 63;
        int grow = row0 + row;
        float4 v = make_float4(0.f, 0.f, 0.f, 0.f);
        if (grow < N_NODES) {
            if (c4 < 32) v = mean4[grow * 32 + c4];
            else         v = x4[grow * 32 + (c4 - 32)];
        }
        *((float4*)&a_lds[row][c4 * 4]) = v;
    }
    __syncthreads();

    const int tx = tid & 31;    // cols tx*4 .. +3
    const int ty = tid >> 5;    // rows ty*8 .. +7
    float4 acc[8];
#pragma unroll
    for (int i = 0; i < 8; i++) acc[i] = make_float4(0.f, 0.f, 0.f, 0.f);

    const float4* Wl4 = (const float4*)W1l;   // [128][32 float4]
    const float4* Wr4 = (const float4*)W1r;

    for (int k4 = 0; k4 < 32; k4++) {
        float4 wl0 = Wl4[(k4 * 4 + 0) * 32 + tx];
        float4 wl1 = Wl4[(k4 * 4 + 1) * 32 + tx];
        float4 wl2 = Wl4[(k4 * 4 + 2) * 32 + tx];
        float4 wl3 = Wl4[(k4 * 4 + 3) * 32 + tx];
        float4 wr0 = Wr4[(k4 * 4 + 0) * 32 + tx];
        float4 wr1 = Wr4[(k4 * 4 + 1) * 32 + tx];
        float4 wr2 = Wr4[(k4 * 4 + 2) * 32 + tx];
        float4 wr3 = Wr4[(k4 * 4 + 3) * 32 + tx];
#pragma unroll
        for (int i = 0; i < 8; i++) {
            float4 al = *((const float4*)&a_lds[ty * 8 + i][k4 * 4]);
            float4 ar = *((const float4*)&a_lds[ty * 8 + i][128 + k4 * 4]);
            acc[i].x += al.x*wl0.x + al.y*wl1.x + al.z*wl2.x + al.w*wl3.x
                      + ar.x*wr0.x + ar.y*wr1.x + ar.z*wr2.x + ar.w*wr3.x;
            acc[i].y += al.x*wl0.y + al.y*wl1.y + al.z*wl2.y + al.w*wl3.y
                      + ar.x*wr0.y + ar.y*wr1.y + ar.z*wr2.y + ar.w*wr3.y;
            acc[i].z += al.x*wl0.z + al.y*wl1.z + al.z*wl2.z + al.w*wl3.z
                      + ar.x*wr0.z + ar.y*wr1.z + ar.z*wr2.z + ar.w*wr3.z;
            acc[i].w += al.x*wl0.w + al.y*wl1.w + al.z*wl2.w + al.w*wl3.w
                      + ar.x*wr0.w + ar.y*wr1.w + ar.z*wr2.w + ar.w*wr3.w;
        }
    }

    float4 bias = ((const float4*)b1)[tx];
    float4* h4 = (float4*)h;
#pragma unroll
    for (int i = 0; i < 8; i++) {
        int grow = row0 + ty * 8 + i;
        if (grow < N_NODES) {
            float4 r;
            r.x = fmaxf(acc[i].x + bias.x, 0.f);
            r.y = fmaxf(acc[i].y + bias.y, 0.f);
            r.z = fmaxf(acc[i].z + bias.z, 0.f);
            r.w = fmaxf(acc[i].w + bias.w, 0.f);
            h4[grow * 32 + tx] = r;
        }
    }
}

// ---------------------------------------------------------------------------
// t = h @ W2l ; u = h @ W2r + b2   [M=50000, K=128, N=32+32]
// 64-row tile (64x132 padded), 256 threads = 16 colgroups x 16 rowgroups,
// thread rows are ty + 16*i so a wave's 4 distinct LDS addrs hit 4 banks.
__global__ __launch_bounds__(256) void k_gemm_t(const float* __restrict__ h,
                                                const float* __restrict__ W2l,
                                                const float* __restrict__ W2r,
                                                const float* __restrict__ b2,
                                                float* __restrict__ tmat,
                                                float* __restrict__ umat) {
    __shared__ float a_lds[64][132];
    const int tid = threadIdx.x;
    const int row0 = blockIdx.x * 64;

    const float4* h4 = (const float4*)h;
#pragma unroll
    for (int m = 0; m < 8; m++) {
        int idx = m * 256 + tid;
        int row = idx >> 5;
        int c4  = idx & 31;
        int grow = row0 + row;
        float4 v = make_float4(0.f, 0.f, 0.f, 0.f);
        if (grow < N_NODES) v = h4[grow * 32 + c4];
        *((float4*)&a_lds[row][c4 * 4]) = v;
    }
    __syncthreads();

    const int tx = tid & 15;    // 16 col groups over 64 cols
    const int ty = tid >> 4;    // 16 row groups, rows ty + 16*i
    const float4* W4 = (tx < 8) ? (const float4*)W2l : (const float4*)W2r;
    const int col4 = (tx < 8) ? tx : tx - 8;

    float4 acc[4];
#pragma unroll
    for (int i = 0; i < 4; i++) acc[i] = make_float4(0.f, 0.f, 0.f, 0.f);

    for (int k4 = 0; k4 < 32; k4++) {
        float4 w0 = W4[(k4 * 4 + 0) * 8 + col4];
        float4 w1 = W4[(k4 * 4 + 1) * 8 + col4];
        float4 w2 = W4[(k4 * 4 + 2) * 8 + col4];
        float4 w3 = W4[(k4 * 4 + 3) * 8 + col4];
#pragma unroll
        for (int i = 0; i < 4; i++) {
            float4 av = *((const float4*)&a_lds[ty + 16 * i][k4 * 4]);
            acc[i].x += av.x*w0.x + av.y*w1.x + av.z*w2.x + av.w*w3.x;
            acc[i].y += av.x*w0.y + av.y*w1.y + av.z*w2.y + av.w*w3.y;
            acc[i].z += av.x*w0.z + av.y*w1.z + av.z*w2.z + av.w*w3.z;
            acc[i].w += av.x*w0.w + av.y*w1.w + av.z*w2.w + av.w*w3.w;
        }
    }

    if (tx < 8) {
        float4* t4 = (float4*)tmat;
#pragma unroll
        for (int i = 0; i < 4; i++) {
            int grow = row0 + ty + 16 * i;
            if (grow < N_NODES) t4[grow * 8 + col4] = acc[i];
        }
    } else {
        float4 bias = ((const float4*)b2)[col4];
        float4* u4 = (float4*)umat;
#pragma unroll
        for (int i = 0; i < 4; i++) {
            int grow = row0 + ty + 16 * i;
            if (grow < N_NODES) {
                float4 r;
                r.x = acc[i].x + bias.x; r.y = acc[i].y + bias.y;
                r.z = acc[i].z + bias.z; r.w = acc[i].w + bias.w;
                u4[grow * 8 + col4] = r;
            }
        }
    }
}

// ---------------------------------------------------------------------------
// out = log_softmax(agg(t)/cnt + u)  — 32 lanes per node, 128B gathers.
__global__ __launch_bounds__(256) void k_out(const float* __restrict__ tmat,
                                             const float* __restrict__ umat,
                                             const int* __restrict__ csr_src,
                                             const int* __restrict__ rowstart,
                                             float* __restrict__ out) {
    int node = blockIdx.x * 8 + (threadIdx.x >> 5);
    if (node >= N_NODES) return;
    int ch = threadIdx.x & 31;
    int s = rowstart[node];
    int e = rowstart[node + 1];
    float sum = 0.f;
    for (int base = s; base < e; base += 32) {
        int idx = (base + ch < e) ? csr_src[base + ch] : 0;
        int m = e - base; if (m > 32) m = 32;
        for (int q = 0; q < m; q++) {
            int src = __shfl(idx, q, 32);
            sum += tmat[src * 32 + ch];
        }
    }
    float val = sum / fmaxf((float)(e - s), 1.0f) + umat[node * 32 + ch];
    float mx = val;
#pragma unroll
    for (int o = 16; o > 0; o >>= 1) mx = fmaxf(mx, __shfl_xor(mx, o, 32));
    float ex = __expf(val - mx);
    float ssum = ex;
#pragma unroll
    for (int o = 16; o > 0; o >>= 1) ssum += __shfl_xor(ssum, o, 32);
    out[node * 32 + ch] = val - mx - logf(ssum);
}

// ---------------------------------------------------------------------------
extern "C" void kernel_launch(void* const* d_in, const int* in_sizes, int n_in,
                              void* d_out, int out_size, void* d_ws, size_t ws_size,
                              hipStream_t stream) {
    const float* x     = (const float*)d_in[0];
    const int*   edges = (const int*)d_in[1];     // [2][E] int32
    const float* W1l   = (const float*)d_in[2];
    const float* W1r   = (const float*)d_in[3];
    const float* b1    = (const float*)d_in[4];
    const float* W2l   = (const float*)d_in[5];
    const float* W2r   = (const float*)d_in[6];
    const float* b2    = (const float*)d_in[7];
    float* out = (float*)d_out;

    char* ws = (char*)d_ws;
    size_t off = 0;
    auto alloc = [&](size_t bytes) { size_t p = off; off += (bytes + 255) & ~(size_t)255; return p; };
    size_t deg_off = alloc(sizeof(int) * N_NODES);
    int*   deg      = (int*)(ws + deg_off);
    size_t cur_off = alloc(sizeof(int) * N_NODES);
    int*   cursor   = (int*)(ws + cur_off);
    size_t zero_bytes = cur_off + sizeof(int) * N_NODES;   // deg..cursor span
    int*   chunksum = (int*)(ws + alloc(sizeof(int) * NCHUNK));
    int*   chunkoff = (int*)(ws + alloc(sizeof(int) * NCHUNK));
    int*   rowstart = (int*)(ws + alloc(sizeof(int) * (N_NODES + 1)));
    int*   csr_src  = (int*)(ws + alloc(sizeof(int) * N_EDGES));
    float* mean     = (float*)(ws + alloc(sizeof(float) * (size_t)N_NODES * HID_CH));
    float* h        = (float*)(ws + alloc(sizeof(float) * (size_t)N_NODES * HID_CH));
    // t/u alias the mean buffer (dead after k_gemm_hidden): 2 x 1.6M floats <= 6.4M
    float* tmat = mean;
    float* umat = mean + (size_t)N_NODES * OUT_CH;

    hipMemsetAsync(ws, 0, zero_bytes, stream);   // deg + cursor in one shot

    const int eblocks = (N_EDGES + 255) / 256;
    k_degree<<<eblocks, 256, 0, stream>>>(edges, deg);
    k_chunksum<<<NCHUNK, 256, 0, stream>>>(deg, chunksum);
    k_chunkscan<<<1, 256, 0, stream>>>(chunksum, chunkoff, rowstart);
    k_rowstart<<<NCHUNK, 256, 0, stream>>>(deg, chunkoff, rowstart);
    k_fill<<<eblocks, 256, 0, stream>>>(edges, rowstart, cursor, csr_src);

    // layer 1
    k_agg<<<(N_NODES + 3) / 4, 256, 0, stream>>>(x, csr_src, rowstart, mean);
    k_gemm_hidden<<<(N_NODES + 63) / 64, 256, 0, stream>>>(mean, x, W1l, W1r, b1, h);

    // layer 2: transform (128->64) then light aggregate + fused log_softmax
    k_gemm_t<<<(N_NODES + 63) / 64, 256, 0, stream>>>(h, W2l, W2r, b2, tmat, umat);
    k_out<<<(N_NODES + 7) / 8, 256, 0, stream>>>(tmat, umat, csr_src, rowstart, out);
}

// Round 3
// 343.271 us; speedup vs baseline: 1.6146x; 1.0058x over previous
//
#include <hip/hip_runtime.h>
#include <hip/hip_bf16.h>

#define N_NODES 50000
#define N_EDGES 800000
#define IN_CH   128
#define HID_CH  128
#define OUT_CH  32
#define NCHUNK  196   // ceil(50000/256)
#define LDSPAD  132   // 128 + 4: wave row-addresses spread across banks

// ---------------------------------------------------------------------------
// CSR build
__global__ void k_degree(const int* __restrict__ edges, int* __restrict__ deg) {
    int e = blockIdx.x * blockDim.x + threadIdx.x;
    if (e >= N_EDGES) return;
    atomicAdd(&deg[edges[N_EDGES + e]], 1);
}

__global__ __launch_bounds__(256) void k_chunksum(const int* __restrict__ deg,
                                                  int* __restrict__ chunksum) {
    int t = threadIdx.x;
    int i = blockIdx.x * 256 + t;
    int v = (i < N_NODES) ? deg[i] : 0;
#pragma unroll
    for (int off = 32; off > 0; off >>= 1) v += __shfl_down(v, off, 64);
    __shared__ int p[4];
    if ((t & 63) == 0) p[t >> 6] = v;
    __syncthreads();
    if (t == 0) chunksum[blockIdx.x] = p[0] + p[1] + p[2] + p[3];
}

__global__ __launch_bounds__(256) void k_chunkscan(const int* __restrict__ chunksum,
                                                   int* __restrict__ chunkoff,
                                                   int* __restrict__ rowstart) {
    __shared__ int s[256];
    int t = threadIdx.x;
    int v = (t < NCHUNK) ? chunksum[t] : 0;
    s[t] = v;
    __syncthreads();
    for (int off = 1; off < 256; off <<= 1) {
        int u = (t >= off) ? s[t - off] : 0;
        __syncthreads();
        s[t] += u;
        __syncthreads();
    }
    if (t < NCHUNK) chunkoff[t] = s[t] - v;
    if (t == 255) rowstart[N_NODES] = s[255];
}

__global__ __launch_bounds__(256) void k_rowstart(const int* __restrict__ deg,
                                                  const int* __restrict__ chunkoff,
                                                  int* __restrict__ rowstart) {
    __shared__ int s[256];
    int t = threadIdx.x;
    int i = blockIdx.x * 256 + t;
    int v = (i < N_NODES) ? deg[i] : 0;
    s[t] = v;
    __syncthreads();
    for (int off = 1; off < 256; off <<= 1) {
        int u = (t >= off) ? s[t - off] : 0;
        __syncthreads();
        s[t] += u;
        __syncthreads();
    }
    if (i < N_NODES) rowstart[i] = chunkoff[blockIdx.x] + s[t] - v;
}

__global__ void k_fill(const int* __restrict__ edges, const int* __restrict__ rowstart,
                       int* __restrict__ cursor, int* __restrict__ csr_src) {
    int e = blockIdx.x * blockDim.x + threadIdx.x;
    if (e >= N_EDGES) return;
    int s = edges[e];
    int d = edges[N_EDGES + e];
    int pos = atomicAdd(&cursor[d], 1);
    csr_src[rowstart[d] + pos] = s;
}

// ---------------------------------------------------------------------------
// Layer-1 mean aggregation: 32 lanes x float4 per node (2 nodes/wave),
// coalesced 512B row gathers, 4-way unrolled for memory-level parallelism.
__global__ __launch_bounds__(256) void k_agg(const float* __restrict__ feat,
                                             const int* __restrict__ csr_src,
                                             const int* __restrict__ rowstart,
                                             float* __restrict__ outmean) {
    int node = blockIdx.x * 8 + (threadIdx.x >> 5);
    if (node >= N_NODES) return;
    int lane = threadIdx.x & 31;
    int s = rowstart[node];
    int e = rowstart[node + 1];
    const float4* f4 = (const float4*)feat;
    float4 acc = make_float4(0.f, 0.f, 0.f, 0.f);
    for (int base = s; base < e; base += 32) {
        int idx = (base + lane < e) ? csr_src[base + lane] : 0;
        int m = e - base; if (m > 32) m = 32;
        int q = 0;
        for (; q + 4 <= m; q += 4) {
            int s0 = __shfl(idx, q, 32);
            int s1 = __shfl(idx, q + 1, 32);
            int s2 = __shfl(idx, q + 2, 32);
            int s3 = __shfl(idx, q + 3, 32);
            float4 v0 = f4[s0 * 32 + lane];
            float4 v1 = f4[s1 * 32 + lane];
            float4 v2 = f4[s2 * 32 + lane];
            float4 v3 = f4[s3 * 32 + lane];
            acc.x += (v0.x + v1.x) + (v2.x + v3.x);
            acc.y += (v0.y + v1.y) + (v2.y + v3.y);
            acc.z += (v0.z + v1.z) + (v2.z + v3.z);
            acc.w += (v0.w + v1.w) + (v2.w + v3.w);
        }
        for (; q < m; q++) {
            int sq = __shfl(idx, q, 32);
            float4 v = f4[sq * 32 + lane];
            acc.x += v.x; acc.y += v.y; acc.z += v.z; acc.w += v.w;
        }
    }
    float inv = 1.0f / fmaxf((float)(e - s), 1.0f);
    ((float4*)outmean)[node * 32 + lane] =
        make_float4(acc.x * inv, acc.y * inv, acc.z * inv, acc.w * inv);
}

// ---------------------------------------------------------------------------
// Fused layer-1 GEMM + layer-2 transform:
//   h = relu(mean @ W1l + x @ W1r + b1)   (kept in LDS, never hits global)
//   t = h @ W2l ;  u = h @ W2r + b2
// 64-row tile, [64][132] LDS (33.8 KB), 256 threads.
// Phase 1: 4 rows x 8 cols per thread (rows ty1+16i -> 4 distinct banks).
// Phase 2: 2 rows x 8 cols per thread over N=64 (rows ty2+32i).
__global__ __launch_bounds__(256, 3) void k_layer1(const float* __restrict__ mean,
                                                   const float* __restrict__ x,
                                                   const float* __restrict__ W1l,
                                                   const float* __restrict__ W1r,
                                                   const float* __restrict__ b1,
                                                   const float* __restrict__ W2l,
                                                   const float* __restrict__ W2r,
                                                   const float* __restrict__ b2,
                                                   float* __restrict__ tmat,
                                                   float* __restrict__ umat) {
    __shared__ float a_lds[64][LDSPAD];
    const int tid = threadIdx.x;
    const int row0 = blockIdx.x * 64;

    const int tx1 = tid & 15;   // col group: cols tx1*8 .. +7  (N=128)
    const int ty1 = tid >> 4;   // row group: rows ty1 + 16*i, i=0..3

    float4 acc0[4], acc1[4];    // [row i][cols tx1*8..+3], [.. +4..+7]
#pragma unroll
    for (int i = 0; i < 4; i++) {
        acc0[i] = make_float4(0.f, 0.f, 0.f, 0.f);
        acc1[i] = make_float4(0.f, 0.f, 0.f, 0.f);
    }

    // ---- phase A: mean tile, W1l ----
    {
        const float4* mean4 = (const float4*)mean;
#pragma unroll
        for (int m = 0; m < 8; m++) {
            int idx = m * 256 + tid;
            int row = idx >> 5;
            int c4  = idx & 31;
            int grow = row0 + row;
            float4 v = make_float4(0.f, 0.f, 0.f, 0.f);
            if (grow < N_NODES) v = mean4[grow * 32 + c4];
            *((float4*)&a_lds[row][c4 * 4]) = v;
        }
        __syncthreads();

        const float4* W4 = (const float4*)W1l;   // [128][32 float4]
        for (int k4 = 0; k4 < 32; k4++) {
            float4 wa[4], wb[4];
#pragma unroll
            for (int kk = 0; kk < 4; kk++) {
                wa[kk] = W4[(k4 * 4 + kk) * 32 + tx1 * 2 + 0];
                wb[kk] = W4[(k4 * 4 + kk) * 32 + tx1 * 2 + 1];
            }
#pragma unroll
            for (int i = 0; i < 4; i++) {
                float4 a = *((const float4*)&a_lds[ty1 + 16 * i][k4 * 4]);
                acc0[i].x += a.x*wa[0].x + a.y*wa[1].x + a.z*wa[2].x + a.w*wa[3].x;
                acc0[i].y += a.x*wa[0].y + a.y*wa[1].y + a.z*wa[2].y + a.w*wa[3].y;
                acc0[i].z += a.x*wa[0].z + a.y*wa[1].z + a.z*wa[2].z + a.w*wa[3].z;
                acc0[i].w += a.x*wa[0].w + a.y*wa[1].w + a.z*wa[2].w + a.w*wa[3].w;
                acc1[i].x += a.x*wb[0].x + a.y*wb[1].x + a.z*wb[2].x + a.w*wb[3].x;
                acc1[i].y += a.x*wb[0].y + a.y*wb[1].y + a.z*wb[2].y + a.w*wb[3].y;
                acc1[i].z += a.x*wb[0].z + a.y*wb[1].z + a.z*wb[2].z + a.w*wb[3].z;
                acc1[i].w += a.x*wb[0].w + a.y*wb[1].w + a.z*wb[2].w + a.w*wb[3].w;
            }
        }
        __syncthreads();
    }

    // ---- phase B: x tile, W1r ----
    {
        const float4* x4 = (const float4*)x;
#pragma unroll
        for (int m = 0; m < 8; m++) {
            int idx = m * 256 + tid;
            int row = idx >> 5;
            int c4  = idx & 31;
            int grow = row0 + row;
            float4 v = make_float4(0.f, 0.f, 0.f, 0.f);
            if (grow < N_NODES) v = x4[grow * 32 + c4];
            *((float4*)&a_lds[row][c4 * 4]) = v;
        }
        __syncthreads();

        const float4* W4 = (const float4*)W1r;
        for (int k4 = 0; k4 < 32; k4++) {
            float4 wa[4], wb[4];
#pragma unroll
            for (int kk = 0; kk < 4; kk++) {
                wa[kk] = W4[(k4 * 4 + kk) * 32 + tx1 * 2 + 0];
                wb[kk] = W4[(k4 * 4 + kk) * 32 + tx1 * 2 + 1];
            }
#pragma unroll
            for (int i = 0; i < 4; i++) {
                float4 a = *((const float4*)&a_lds[ty1 + 16 * i][k4 * 4]);
                acc0[i].x += a.x*wa[0].x + a.y*wa[1].x + a.z*wa[2].x + a.w*wa[3].x;
                acc0[i].y += a.x*wa[0].y + a.y*wa[1].y + a.z*wa[2].y + a.w*wa[3].y;
                acc0[i].z += a.x*wa[0].z + a.y*wa[1].z + a.z*wa[2].z + a.w*wa[3].z;
                acc0[i].w += a.x*wa[0].w + a.y*wa[1].w + a.z*wa[2].w + a.w*wa[3].w;
                acc1[i].x += a.x*wb[0].x + a.y*wb[1].x + a.z*wb[2].x + a.w*wb[3].x;
                acc1[i].y += a.x*wb[0].y + a.y*wb[1].y + a.z*wb[2].y + a.w*wb[3].y;
                acc1[i].z += a.x*wb[0].z + a.y*wb[1].z + a.z*wb[2].z + a.w*wb[3].z;
                acc1[i].w += a.x*wb[0].w + a.y*wb[1].w + a.z*wb[2].w + a.w*wb[3].w;
            }
        }
        __syncthreads();
    }

    // ---- h = relu(acc + b1) -> back into LDS ----
    {
        const float4* b14 = (const float4*)b1;
        float4 ba = b14[tx1 * 2 + 0];
        float4 bb = b14[tx1 * 2 + 1];
#pragma unroll
        for (int i = 0; i < 4; i++) {
            int row = ty1 + 16 * i;
            float4 h0, h1;
            h0.x = fmaxf(acc0[i].x + ba.x, 0.f);
            h0.y = fmaxf(acc0[i].y + ba.y, 0.f);
            h0.z = fmaxf(acc0[i].z + ba.z, 0.f);
            h0.w = fmaxf(acc0[i].w + ba.w, 0.f);
            h1.x = fmaxf(acc1[i].x + bb.x, 0.f);
            h1.y = fmaxf(acc1[i].y + bb.y, 0.f);
            h1.z = fmaxf(acc1[i].z + bb.z, 0.f);
            h1.w = fmaxf(acc1[i].w + bb.w, 0.f);
            *((float4*)&a_lds[row][tx1 * 8 + 0]) = h0;
            *((float4*)&a_lds[row][tx1 * 8 + 4]) = h1;
        }
        __syncthreads();
    }

    // ---- phase C: t = h @ W2l ; u = h @ W2r + b2   (N=64) ----
    {
        const int tx2 = tid & 7;    // col group over 64 cols (8 each)
        const int ty2 = tid >> 3;   // rows ty2 + 32*i, i=0..1
        const bool is_u = (tx2 >= 4);
        const float4* W4 = is_u ? (const float4*)W2r : (const float4*)W2l; // [128][8 f4]
        const int c4 = (is_u ? tx2 - 4 : tx2) * 2;

        float4 a20[2], a21[2];
#pragma unroll
        for (int i = 0; i < 2; i++) {
            a20[i] = make_float4(0.f, 0.f, 0.f, 0.f);
            a21[i] = make_float4(0.f, 0.f, 0.f, 0.f);
        }

        for (int k4 = 0; k4 < 32; k4++) {
            float4 wa[4], wb[4];
#pragma unroll
            for (int kk = 0; kk < 4; kk++) {
                wa[kk] = W4[(k4 * 4 + kk) * 8 + c4 + 0];
                wb[kk] = W4[(k4 * 4 + kk) * 8 + c4 + 1];
            }
#pragma unroll
            for (int i = 0; i < 2; i++) {
                float4 a = *((const float4*)&a_lds[ty2 + 32 * i][k4 * 4]);
                a20[i].x += a.x*wa[0].x + a.y*wa[1].x + a.z*wa[2].x + a.w*wa[3].x;
                a20[i].y += a.x*wa[0].y + a.y*wa[1].y + a.z*wa[2].y + a.w*wa[3].y;
                a20[i].z += a.x*wa[0].z + a.y*wa[1].z + a.z*wa[2].z + a.w*wa[3].z;
                a20[i].w += a.x*wa[0].w + a.y*wa[1].w + a.z*wa[2].w + a.w*wa[3].w;
                a21[i].x += a.x*wb[0].x + a.y*wb[1].x + a.z*wb[2].x + a.w*wb[3].x;
                a21[i].y += a.x*wb[0].y + a.y*wb[1].y + a.z*wb[2].y + a.w*wb[3].y;
                a21[i].z += a.x*wb[0].z + a.y*wb[1].z + a.z*wb[2].z + a.w*wb[3].z;
                a21[i].w += a.x*wb[0].w + a.y*wb[1].w + a.z*wb[2].w + a.w*wb[3].w;
            }
        }

        if (!is_u) {
            float4* t4 = (float4*)tmat;
#pragma unroll
            for (int i = 0; i < 2; i++) {
                int grow = row0 + ty2 + 32 * i;
                if (grow < N_NODES) {
                    t4[grow * 8 + c4 + 0] = a20[i];
                    t4[grow * 8 + c4 + 1] = a21[i];
                }
            }
        } else {
            const float4* b24 = (const float4*)b2;
            float4 ba = b24[c4 + 0];
            float4 bb = b24[c4 + 1];
            float4* u4 = (float4*)umat;
#pragma unroll
            for (int i = 0; i < 2; i++) {
                int grow = row0 + ty2 + 32 * i;
                if (grow < N_NODES) {
                    float4 r0, r1;
                    r0.x = a20[i].x + ba.x; r0.y = a20[i].y + ba.y;
                    r0.z = a20[i].z + ba.z; r0.w = a20[i].w + ba.w;
                    r1.x = a21[i].x + bb.x; r1.y = a21[i].y + bb.y;
                    r1.z = a21[i].z + bb.z; r1.w = a21[i].w + bb.w;
                    u4[grow * 8 + c4 + 0] = r0;
                    u4[grow * 8 + c4 + 1] = r1;
                }
            }
        }
    }
}

// ---------------------------------------------------------------------------
// out = log_softmax(agg(t)/cnt + u)  — 32 lanes per node, 128B gathers, x4 MLP.
__global__ __launch_bounds__(256) void k_out(const float* __restrict__ tmat,
                                             const float* __restrict__ umat,
                                             const int* __restrict__ csr_src,
                                             const int* __restrict__ rowstart,
                                             float* __restrict__ out) {
    int node = blockIdx.x * 8 + (threadIdx.x >> 5);
    if (node >= N_NODES) return;
    int ch = threadIdx.x & 31;
    int s = rowstart[node];
    int e = rowstart[node + 1];
    float sum = 0.f;
    for (int base = s; base < e; base += 32) {
        int idx = (base + ch < e) ? csr_src[base + ch] : 0;
        int m = e - base; if (m > 32) m = 32;
        int q = 0;
        for (; q + 4 <= m; q += 4) {
            int s0 = __shfl(idx, q, 32);
            int s1 = __shfl(idx, q + 1, 32);
            int s2 = __shfl(idx, q + 2, 32);
            int s3 = __shfl(idx, q + 3, 32);
            float v0 = tmat[s0 * 32 + ch];
            float v1 = tmat[s1 * 32 + ch];
            float v2 = tmat[s2 * 32 + ch];
            float v3 = tmat[s3 * 32 + ch];
            sum += (v0 + v1) + (v2 + v3);
        }
        for (; q < m; q++) {
            int sq = __shfl(idx, q, 32);
            sum += tmat[sq * 32 + ch];
        }
    }
    float val = sum / fmaxf((float)(e - s), 1.0f) + umat[node * 32 + ch];
    float mx = val;
#pragma unroll
    for (int o = 16; o > 0; o >>= 1) mx = fmaxf(mx, __shfl_xor(mx, o, 32));
    float ex = __expf(val - mx);
    float ssum = ex;
#pragma unroll
    for (int o = 16; o > 0; o >>= 1) ssum += __shfl_xor(ssum, o, 32);
    out[node * 32 + ch] = val - mx - logf(ssum);
}

// ---------------------------------------------------------------------------
extern "C" void kernel_launch(void* const* d_in, const int* in_sizes, int n_in,
                              void* d_out, int out_size, void* d_ws, size_t ws_size,
                              hipStream_t stream) {
    const float* x     = (const float*)d_in[0];
    const int*   edges = (const int*)d_in[1];     // [2][E] int32
    const float* W1l   = (const float*)d_in[2];
    const float* W1r   = (const float*)d_in[3];
    const float* b1    = (const float*)d_in[4];
    const float* W2l   = (const float*)d_in[5];
    const float* W2r   = (const float*)d_in[6];
    const float* b2    = (const float*)d_in[7];
    float* out = (float*)d_out;

    char* ws = (char*)d_ws;
    size_t off = 0;
    auto alloc = [&](size_t bytes) { size_t p = off; off += (bytes + 255) & ~(size_t)255; return p; };
    size_t deg_off = alloc(sizeof(int) * N_NODES);
    int*   deg      = (int*)(ws + deg_off);
    size_t cur_off = alloc(sizeof(int) * N_NODES);
    int*   cursor   = (int*)(ws + cur_off);
    size_t zero_bytes = cur_off + sizeof(int) * N_NODES;   // deg..cursor span
    int*   chunksum = (int*)(ws + alloc(sizeof(int) * NCHUNK));
    int*   chunkoff = (int*)(ws + alloc(sizeof(int) * NCHUNK));
    int*   rowstart = (int*)(ws + alloc(sizeof(int) * (N_NODES + 1)));
    int*   csr_src  = (int*)(ws + alloc(sizeof(int) * N_EDGES));
    float* mean     = (float*)(ws + alloc(sizeof(float) * (size_t)N_NODES * HID_CH));
    float* tmat     = (float*)(ws + alloc(sizeof(float) * (size_t)N_NODES * OUT_CH));
    float* umat     = (float*)(ws + alloc(sizeof(float) * (size_t)N_NODES * OUT_CH));

    hipMemsetAsync(ws, 0, zero_bytes, stream);

    const int eblocks = (N_EDGES + 255) / 256;
    k_degree<<<eblocks, 256, 0, stream>>>(edges, deg);
    k_chunksum<<<NCHUNK, 256, 0, stream>>>(deg, chunksum);
    k_chunkscan<<<1, 256, 0, stream>>>(chunksum, chunkoff, rowstart);
    k_rowstart<<<NCHUNK, 256, 0, stream>>>(deg, chunkoff, rowstart);
    k_fill<<<eblocks, 256, 0, stream>>>(edges, rowstart, cursor, csr_src);

    // layer 1 aggregation
    k_agg<<<(N_NODES + 7) / 8, 256, 0, stream>>>(x, csr_src, rowstart, mean);
    // fused: h (in LDS) -> t = h@W2l, u = h@W2r + b2
    k_layer1<<<(N_NODES + 63) / 64, 256, 0, stream>>>(mean, x, W1l, W1r, b1,
                                                      W2l, W2r, b2, tmat, umat);
    // layer 2 light aggregate + fused log_softmax
    k_out<<<(N_NODES + 7) / 8, 256, 0, stream>>>(tmat, umat, csr_src, rowstart, out);
}